// Round 2
// baseline (866.075 us; speedup 1.0000x reference)
//
#include <hip/hip_runtime.h>

// Problem constants
#define Bn   32
#define Cc   512
#define CIc  256
#define Nsp  3136      // 56*56
#define Npad 3200      // spatial padded to multiple of 128 (tile coverage)
#define EPSbn 1e-5f

typedef __attribute__((ext_vector_type(8))) short v8s;   // 8 x bf16 (4 VGPRs)
typedef __attribute__((ext_vector_type(4))) float v4f;   // MFMA accumulator

__device__ __forceinline__ unsigned short f2bf(float f) {
    unsigned int u = __builtin_bit_cast(unsigned int, f);
    u += 0x7fffu + ((u >> 16) & 1u);          // RNE
    return (unsigned short)(u >> 16);
}

__device__ __forceinline__ float bf2f(unsigned short u) {
    unsigned int x = ((unsigned int)u) << 16;
    return __builtin_bit_cast(float, x);
}

// async global->LDS, 16B per lane; LDS dest = wave-uniform base + lane*16
__device__ __forceinline__ void async16(const unsigned short* g, unsigned short* l) {
    __builtin_amdgcn_global_load_lds(
        (const __attribute__((address_space(1))) unsigned int*)g,
        (__attribute__((address_space(3))) unsigned int*)l, 16, 0, 0);
}

// Canonical bf16 MFMA GEMM:  O[gn][gm] = sum_k A[gm][k] * B[gn][k]
// A: [M][lda] bf16 (k-contig), B: [N][ldb] bf16 (k-contig).
// Block tile 128x128 (M x N), BK=32, 4 waves in 2x2, 4x4 16x16x32 MFMAs/wave.
// EPI 0: bf16 store O[gn][gm] (* scale + optional biasN[bN_bs*b + gn])
// EPI 2: z = acc + biasN[bN_bs*b+gc] + x[b][gc][gsp] (fp32 residual);
//        store z bf16 [c][n] (gsp<Nsp); per-channel sum/sumsq atomics into stats
// EPI 4: bf16 store of acc*scale + u1[b][gn]*w1[gm] + u2[gn]*w2[b][gm]  (rank-2 bias fix)
template <int EPI>
__global__ __launch_bounds__(256)
void mfma_gemm(const unsigned short* __restrict__ A, int lda, long a_bs,
               const unsigned short* __restrict__ B, int ldb, long b_bs,
               void* __restrict__ Out, int ldo, long o_bs,
               int K, float scale,
               const float* __restrict__ biasN, long bN_bs,
               const float* __restrict__ xres,
               float* __restrict__ stats,
               const float* __restrict__ r2u1, const float* __restrict__ r2w1,
               const float* __restrict__ r2u2, const float* __restrict__ r2w2)
{
    __shared__ __align__(16) unsigned short As[128 * 32];  // [m][k] 8KB
    __shared__ __align__(16) unsigned short Bs[128 * 32];  // [n][k] 8KB

    const int tid  = threadIdx.x;
    const int w    = tid >> 6;
    const int lane = tid & 63;
    const int b    = blockIdx.z;
    const int m0   = blockIdx.x * 128;
    const int n0   = blockIdx.y * 128;

    const unsigned short* Ab = A + (long)b * a_bs;
    const unsigned short* Bb = B + (long)b * b_bs;

    // staging map: chunk c = 2w+q covers LDS elems [c*512,(c+1)*512), lane elem = c*512+lane*8
    const int ldrow = 32 * w + (lane >> 2);
    const int ldk   = (lane & 3) * 8;
    unsigned short* lA0 = &As[(2 * w + 0) * 512];
    unsigned short* lA1 = &As[(2 * w + 1) * 512];
    unsigned short* lB0 = &Bs[(2 * w + 0) * 512];
    unsigned short* lB1 = &Bs[(2 * w + 1) * 512];
    const size_t aoff0 = (size_t)(m0 + ldrow) * lda + ldk;
    const size_t aoff1 = aoff0 + (size_t)16 * lda;
    const size_t boff0 = (size_t)(n0 + ldrow) * ldb + ldk;
    const size_t boff1 = boff0 + (size_t)16 * ldb;

    const int wm = (w & 1) * 64;       // wave tile M offset
    const int wn = (w >> 1) * 64;      // wave tile N offset
    const int fr = lane & 15;
    const int fk = (lane >> 4) * 8;

    v4f acc[4][4] = {};

    for (int k0 = 0; k0 < K; k0 += 32) {
        __syncthreads();                        // previous tile's ds_reads done
        async16(Ab + aoff0 + k0, lA0);
        async16(Ab + aoff1 + k0, lA1);
        async16(Bb + boff0 + k0, lB0);
        async16(Bb + boff1 + k0, lB1);
        __syncthreads();                        // drains vmcnt -> LDS valid

        v8s af[4], bf[4];
#pragma unroll
        for (int i = 0; i < 4; ++i)
            af[i] = *(const v8s*)&As[(wm + i * 16 + fr) * 32 + fk];
#pragma unroll
        for (int j = 0; j < 4; ++j)
            bf[j] = *(const v8s*)&Bs[(wn + j * 16 + fr) * 32 + fk];
#pragma unroll
        for (int i = 0; i < 4; ++i)
#pragma unroll
            for (int j = 0; j < 4; ++j)
                acc[i][j] = __builtin_amdgcn_mfma_f32_16x16x32_bf16(af[i], bf[j], acc[i][j], 0, 0, 0);
    }

    // C/D layout: col(n-role)=lane&15, row(m-role)=quad*4+reg -> 4 consecutive m per lane
    const int em = wm + ((lane >> 4) << 2);
    const int en = wn + fr;

    if constexpr (EPI == 0) {
        unsigned short* O = (unsigned short*)Out;
#pragma unroll
        for (int j = 0; j < 4; ++j) {
            const int gn = n0 + en + j * 16;
            const float bN = biasN ? biasN[bN_bs * b + gn] : 0.0f;
            unsigned short* orow = O + (long)b * o_bs + (size_t)gn * ldo + m0 + em;
#pragma unroll
            for (int i = 0; i < 4; ++i) {
                ushort4 o4;
                o4.x = f2bf(acc[i][j].x * scale + bN);
                o4.y = f2bf(acc[i][j].y * scale + bN);
                o4.z = f2bf(acc[i][j].z * scale + bN);
                o4.w = f2bf(acc[i][j].w * scale + bN);
                *(ushort4*)&orow[i * 16] = o4;
            }
        }
    } else if constexpr (EPI == 4) {
        unsigned short* O = (unsigned short*)Out;
#pragma unroll
        for (int j = 0; j < 4; ++j) {
            const int gn = n0 + en + j * 16;                 // f index
            const float uu1 = r2u1[(size_t)b * Cc + gn];
            const float uu2 = r2u2[gn];
            unsigned short* orow = O + (long)b * o_bs + (size_t)gn * ldo + m0 + em;
#pragma unroll
            for (int i = 0; i < 4; ++i) {
                const int e0 = m0 + em + i * 16;             // e index base
                const float4 w1v = *(const float4*)&r2w1[e0];
                const float4 w2v = *(const float4*)&r2w2[(size_t)b * Cc + e0];
                ushort4 o4;
                o4.x = f2bf(acc[i][j].x * scale + uu1 * w1v.x + uu2 * w2v.x);
                o4.y = f2bf(acc[i][j].y * scale + uu1 * w1v.y + uu2 * w2v.y);
                o4.z = f2bf(acc[i][j].z * scale + uu1 * w1v.z + uu2 * w2v.z);
                o4.w = f2bf(acc[i][j].w * scale + uu1 * w1v.w + uu2 * w2v.w);
                *(ushort4*)&orow[i * 16] = o4;
            }
        }
    } else {  // EPI == 2: z = acc + c0[b][c] + x residual (fp32); store bf16 z; BN stats
        unsigned short* O = (unsigned short*)Out;
        float sj[4] = {0.f, 0.f, 0.f, 0.f}, qj[4] = {0.f, 0.f, 0.f, 0.f};
#pragma unroll
        for (int j = 0; j < 4; ++j) {
            const int gc = n0 + en + j * 16;
            const float wb = biasN[bN_bs * b + gc];
            const float* xrow = xres + (size_t)b * Cc * Nsp + (size_t)gc * Nsp;
            unsigned short* zrow = O + (long)b * o_bs + (size_t)gc * ldo;
#pragma unroll
            for (int i = 0; i < 4; ++i) {
                const int gsp = m0 + em + i * 16;
                if (gsp < Nsp) {
                    const float4 xr = *(const float4*)&xrow[gsp];
                    const float z0 = acc[i][j].x + wb + xr.x;
                    const float z1 = acc[i][j].y + wb + xr.y;
                    const float z2 = acc[i][j].z + wb + xr.z;
                    const float z3 = acc[i][j].w + wb + xr.w;
                    sj[j] += z0 + z1 + z2 + z3;
                    qj[j] += z0 * z0 + z1 * z1 + z2 * z2 + z3 * z3;
                    ushort4 o4;
                    o4.x = f2bf(z0); o4.y = f2bf(z1); o4.z = f2bf(z2); o4.w = f2bf(z3);
                    *(ushort4*)&zrow[gsp] = o4;
                }
            }
        }
        __syncthreads();                       // done reading As -> reuse as scratch
        float* red = (float*)As;               // [128][8] sums + [128][8] sumsq (8KB exactly)
        const int cid = (lane >> 4) + ((w & 1) << 2);
#pragma unroll
        for (int j = 0; j < 4; ++j) {
            const int cc = wn + fr + j * 16;
            red[cc * 8 + cid] = sj[j];
            red[1024 + cc * 8 + cid] = qj[j];
        }
        __syncthreads();
        if (tid < 128) {
            float s = 0.f, q = 0.f;
#pragma unroll
            for (int t = 0; t < 8; ++t) { s += red[tid * 8 + t]; q += red[1024 + tid * 8 + t]; }
            atomicAdd(&stats[n0 + tid], s);
            atomicAdd(&stats[Cc + n0 + tid], q);
        }
    }
}

// x fp32 [b][c][n] -> xT bf16 [b][n][c] AND x16 bf16 [b][c][n]; accumulates
// per-channel row sums r[b][c] += sum_n x[b][c][n] (for exact bias correction).
__global__ __launch_bounds__(256)
void cast_transpose(const float* __restrict__ x, unsigned short* __restrict__ xT,
                    unsigned short* __restrict__ x16, float* __restrict__ r)
{
    __shared__ float tile[64][65];
    const int b  = blockIdx.z;
    const int n0 = blockIdx.x * 64;
    const int c0 = blockIdx.y * 64;
    const float* xb = x + (size_t)b * Cc * Nsp;
    unsigned short* x16b = x16 + (size_t)b * Cc * Nsp;
    const int t = threadIdx.x;
    const int tr  = t >> 4;            // 0..15
    const int tc4 = (t & 15) * 4;
#pragma unroll
    for (int i = 0; i < 4; ++i) {
        const int c = tr + i * 16;
        const float4 v = *(const float4*)&xb[(size_t)(c0 + c) * Nsp + n0 + tc4];
        tile[tc4 + 0][c] = v.x;
        tile[tc4 + 1][c] = v.y;
        tile[tc4 + 2][c] = v.z;
        tile[tc4 + 3][c] = v.w;
        ushort4 s;
        s.x = f2bf(v.x); s.y = f2bf(v.y); s.z = f2bf(v.z); s.w = f2bf(v.w);
        *(ushort4*)&x16b[(size_t)(c0 + c) * Nsp + n0 + tc4] = s;
    }
    __syncthreads();
    if (t < 64) {                      // per-channel partial sums of this tile
        float s = 0.f;
#pragma unroll 8
        for (int n = 0; n < 64; ++n) s += tile[n][t];
        atomicAdd(&r[(size_t)b * Cc + c0 + t], s);
    }
    unsigned short* xo = xT + (size_t)b * Nsp * Cc;
#pragma unroll
    for (int i = 0; i < 4; ++i) {
        const int n = tr + i * 16;
        ushort4 o;
        o.x = f2bf(tile[n][tc4 + 0]);
        o.y = f2bf(tile[n][tc4 + 1]);
        o.z = f2bf(tile[n][tc4 + 2]);
        o.w = f2bf(tile[n][tc4 + 3]);
        *(ushort4*)&xo[(size_t)(n0 + n) * Cc + c0 + tc4] = o;
    }
}

__global__ void cast_w(const float* __restrict__ src, unsigned short* __restrict__ dst, int n)
{
    const int i = (blockIdx.x * 256 + threadIdx.x) * 4;
    if (i < n) {
        const float4 v = *(const float4*)&src[i];
        ushort4 o;
        o.x = f2bf(v.x); o.y = f2bf(v.y); o.z = f2bf(v.z); o.w = f2bf(v.w);
        *(ushort4*)&dst[i] = o;
    }
}

// src fp32 [256][512] -> dst bf16 [512][256] transposed (tiny)
__global__ void cast_wT(const float* __restrict__ src, unsigned short* __restrict__ dst)
{
    const int c = blockIdx.x;          // 512
    const int d = threadIdx.x;         // 256
    dst[(size_t)c * CIc + d] = f2bf(src[(size_t)d * Cc + c]);
}

// Batch-independent bias vectors: w1 = g_w^T ph_b, q = ph_w^T g_b, u2 = W_w th_b,
// pbgb = ph_b . g_b   (all zero when biases are zero)
__global__ void k_vec1(const float* __restrict__ g_w, const float* __restrict__ ph_w,
                       const float* __restrict__ W_w, const float* __restrict__ th_b,
                       const float* __restrict__ ph_b, const float* __restrict__ g_b,
                       float* __restrict__ w1, float* __restrict__ q,
                       float* __restrict__ u2, float* __restrict__ pbgb)
{
    const int t = threadIdx.x;  // 512
    float a = 0.f, bq = 0.f;
    for (int d = 0; d < CIc; ++d) {
        a  += g_w[(size_t)d * Cc + t] * ph_b[d];
        bq += ph_w[(size_t)d * Cc + t] * g_b[d];
    }
    w1[t] = a; q[t] = bq;
    float u = 0.f;
    for (int c = 0; c < CIc; ++c) u += W_w[(size_t)t * CIc + c] * th_b[c];
    u2[t] = u;
    if (t == 0) {
        float s = 0.f;
        for (int d = 0; d < CIc; ++d) s += ph_b[d] * g_b[d];
        *pbgb = s;
    }
}

// Per-batch bias vectors: u1 = WT r / N, w2 = PG^T r / N + w1,
// c0 = W_w * fgb + W_b where fgb = (Th(Sq) + pbgb*(Th r) + (r.q) th_b)/N + pbgb*th_b
__global__ void k_vecb(const unsigned short* __restrict__ S, const unsigned short* __restrict__ WT,
                       const unsigned short* __restrict__ PGt, const float* __restrict__ r,
                       const float* __restrict__ w1, const float* __restrict__ q,
                       const float* __restrict__ pbgb,
                       const float* __restrict__ th_w, const float* __restrict__ th_b,
                       const float* __restrict__ W_w, const float* __restrict__ W_b,
                       float* __restrict__ u1, float* __restrict__ w2, float* __restrict__ c0)
{
    const int b = blockIdx.x, t = threadIdx.x;   // 512 threads
    __shared__ float sq[Cc];
    __shared__ float fgb[CIc];
    __shared__ float s_rq;
    const float invN = 1.0f / (float)Nsp;
    const float* rb = r + (size_t)b * Cc;

    float aq = 0.f;
    const unsigned short* Sr = S + (size_t)b * Cc * Cc + (size_t)t * Cc;
    for (int c2 = 0; c2 < Cc; ++c2) aq += bf2f(Sr[c2]) * q[c2];
    sq[t] = aq;

    float a1 = 0.f;
    const unsigned short* WTr = WT + (size_t)t * Cc;
    for (int c1 = 0; c1 < Cc; ++c1) a1 += bf2f(WTr[c1]) * rb[c1];
    u1[(size_t)b * Cc + t] = a1 * invN;

    float a2 = 0.f;
    const unsigned short* PGr = PGt + (size_t)t * Cc;
    for (int c2 = 0; c2 < Cc; ++c2) a2 += bf2f(PGr[c2]) * rb[c2];
    w2[(size_t)b * Cc + t] = a2 * invN + w1[t];

    if (t == 0) {
        float s = 0.f;
        for (int c2 = 0; c2 < Cc; ++c2) s += rb[c2] * q[c2];
        s_rq = s;
    }
    __syncthreads();
    if (t < CIc) {
        float ts = 0.f, tr2 = 0.f;
        const float* thr = th_w + (size_t)t * Cc;
        for (int c1 = 0; c1 < Cc; ++c1) { ts += thr[c1] * sq[c1]; tr2 += thr[c1] * rb[c1]; }
        const float pg = *pbgb;
        fgb[t] = (ts + pg * tr2 + s_rq * th_b[t]) * invN + pg * th_b[t];
    }
    __syncthreads();
    float cacc = 0.f;
    const float* Wr = W_w + (size_t)t * CIc;
    for (int d = 0; d < CIc; ++d) cacc += Wr[d] * fgb[d];
    c0[(size_t)b * Cc + t] = cacc + W_b[t];
}

__global__ void finalize_stats(const float* __restrict__ stats, float* __restrict__ mstd)
{
    const int c = threadIdx.x;  // 512
    const float inv = 1.0f / (float)((long)Bn * Nsp);
    const float mean = stats[c] * inv;
    const float var  = stats[Cc + c] * inv - mean * mean;
    mstd[c] = mean;
    mstd[Cc + c] = rsqrtf(var + EPSbn);
}

// out[b][c][n] = (z16[b][c][n] - mean[c]) * rstd[c] * gamma[c] + beta[c]
__global__ __launch_bounds__(256)
void bnorm_apply(const unsigned short* __restrict__ z, const float* __restrict__ mstd,
                 const float* __restrict__ gamma, const float* __restrict__ beta,
                 float* __restrict__ out)
{
    const int NG = Bn * Cc * (Nsp / 8);            // groups of 8
    const int g = blockIdx.x * 256 + threadIdx.x;
    if (g >= NG) return;
    const int c = (g / (Nsp / 8)) & (Cc - 1);
    const float a1 = mstd[Cc + c] * gamma[c];
    const float a0 = beta[c] - mstd[c] * a1;
    const v8s zv = *(const v8s*)(z + (size_t)g * 8);
    float* op = out + (size_t)g * 8;
    float4 o0, o1;
    o0.x = bf2f((unsigned short)zv[0]) * a1 + a0;
    o0.y = bf2f((unsigned short)zv[1]) * a1 + a0;
    o0.z = bf2f((unsigned short)zv[2]) * a1 + a0;
    o0.w = bf2f((unsigned short)zv[3]) * a1 + a0;
    o1.x = bf2f((unsigned short)zv[4]) * a1 + a0;
    o1.y = bf2f((unsigned short)zv[5]) * a1 + a0;
    o1.z = bf2f((unsigned short)zv[6]) * a1 + a0;
    o1.w = bf2f((unsigned short)zv[7]) * a1 + a0;
    *(float4*)op = o0;
    *(float4*)(op + 4) = o1;
}

extern "C" void kernel_launch(void* const* d_in, const int* in_sizes, int n_in,
                              void* d_out, int out_size, void* d_ws, size_t ws_size,
                              hipStream_t stream)
{
    const float* x     = (const float*)d_in[0];
    const float* g_w   = (const float*)d_in[1];
    const float* g_b   = (const float*)d_in[2];
    const float* th_w  = (const float*)d_in[3];
    const float* th_b  = (const float*)d_in[4];
    const float* ph_w  = (const float*)d_in[5];
    const float* ph_b  = (const float*)d_in[6];
    const float* W_w   = (const float*)d_in[7];
    const float* W_b   = (const float*)d_in[8];
    const float* gamma = (const float*)d_in[9];
    const float* beta  = (const float*)d_in[10];
    float* out = (float*)d_out;

    // Full algebraic collapse (block is linear in x per batch):
    //   S_b = x_b x_b^T  (channel Gram, [512][512], K=3136)
    //   A_b = WT * S_b * PG / N + u1 w1^T + u2 w2^T    (WT=W th_w, PG=ph_w^T g_w, batch-indep)
    //   z_b = A_b x_b + c0_b + x_b ;  out = BN(z)
    // Rank-2 terms + c0 handle all conv biases exactly (zero in this harness).
    //
    // ws layout (bf16 elems):
    //  xT  [32][3136][512] (+64 rows pad)  ~102.8 MB
    //  x16 [32][512][3136]                 ~102.8 MB   (later reused as Rt, then z16)
    //  S   [32][512][512]                   16.8 MB    (later reused as Afull)
    //  WT [512][512], PGt [512][512], thwT/phwT/gwT [512][256], Ww16 [512][256]
    //  fp32: r[32*512], w1/q/u2[512 each], pbgb, u1/w2/c0[32*512 each], stats, mstd
    unsigned short* xT   = (unsigned short*)d_ws;
    unsigned short* x16  = xT + (size_t)Bn * Nsp * Cc + 64 * Cc;   // pad for M=3200 OOB reads
    unsigned short* S    = x16 + (size_t)Bn * Cc * Nsp;
    unsigned short* WT   = S + (size_t)Bn * Cc * Cc;
    unsigned short* PGt  = WT + (size_t)Cc * Cc;
    unsigned short* thwT = PGt + (size_t)Cc * Cc;
    unsigned short* phwT = thwT + (size_t)Cc * CIc;
    unsigned short* gwT  = phwT + (size_t)Cc * CIc;
    unsigned short* Ww16 = gwT + (size_t)Cc * CIc;
    float* r    = (float*)(Ww16 + (size_t)Cc * CIc);
    float* w1   = r + Bn * Cc;
    float* q    = w1 + Cc;
    float* u2v  = q + Cc;
    float* pbgb = u2v + Cc;
    float* u1v  = pbgb + 4;
    float* w2v  = u1v + Bn * Cc;
    float* c0   = w2v + Bn * Cc;
    float* stats = c0 + Bn * Cc;
    float* mstd  = stats + 2 * Cc;

    unsigned short* Rt    = x16;   // x16 dead after S GEMM
    unsigned short* Afull = S;     // S dead after Rt GEMM + k_vecb
    unsigned short* z16   = x16;   // Rt dead after Afull GEMM

    hipMemsetAsync(stats, 0, 2 * Cc * sizeof(float), stream);
    hipMemsetAsync(r, 0, (size_t)Bn * Cc * sizeof(float), stream);

    const dim3 blk(256);
    const long xT_bs  = (long)Nsp * Cc;
    const long x16_bs = (long)Cc * Nsp;
    const long sq_bs  = (long)Cc * Cc;   // 512x512 per-batch matrices

    cast_transpose<<<dim3(49, 8, Bn), blk, 0, stream>>>(x, xT, x16, r);
    cast_w<<<dim3(128), blk, 0, stream>>>(W_w, Ww16, Cc * CIc);
    cast_wT<<<dim3(Cc), dim3(CIc), 0, stream>>>(th_w, thwT);
    cast_wT<<<dim3(Cc), dim3(CIc), 0, stream>>>(ph_w, phwT);
    cast_wT<<<dim3(Cc), dim3(CIc), 0, stream>>>(g_w, gwT);
    k_vec1<<<dim3(1), dim3(Cc), 0, stream>>>(g_w, ph_w, W_w, th_b, ph_b, g_b, w1, q, u2v, pbgb);

    // WT[f][c1] = sum_c th_w[c][c1] W_w[f][c]   (batch-indep, grid z=1)
    mfma_gemm<0><<<dim3(4, 4, 1), blk, 0, stream>>>(
        thwT, CIc, 0, Ww16, CIc, 0, WT, Cc, 0, CIc, 1.0f,
        nullptr, 0, nullptr, nullptr, nullptr, nullptr, nullptr, nullptr);
    // PGt[e][c2] = sum_d ph_w[d][c2] g_w[d][e]
    mfma_gemm<0><<<dim3(4, 4, 1), blk, 0, stream>>>(
        phwT, CIc, 0, gwT, CIc, 0, PGt, Cc, 0, CIc, 1.0f,
        nullptr, 0, nullptr, nullptr, nullptr, nullptr, nullptr, nullptr);
    // S[c2][c1] = sum_n x16[c1][n] x16[c2][n]   (symmetric)
    mfma_gemm<0><<<dim3(4, 4, Bn), blk, 0, stream>>>(
        x16, Nsp, x16_bs, x16, Nsp, x16_bs, S, Cc, sq_bs, Nsp, 1.0f,
        nullptr, 0, nullptr, nullptr, nullptr, nullptr, nullptr, nullptr);
    // Rt[e][c1] = sum_c2 S[c1][c2] PGt[e][c2]   (R = S*PG, stored transposed)
    mfma_gemm<0><<<dim3(4, 4, Bn), blk, 0, stream>>>(
        S, Cc, sq_bs, PGt, Cc, 0, Rt, Cc, sq_bs, Cc, 1.0f,
        nullptr, 0, nullptr, nullptr, nullptr, nullptr, nullptr, nullptr);
    // per-batch bias vectors (needs S, WT, PGt, r) -- before Afull overwrites S
    k_vecb<<<dim3(Bn), dim3(Cc), 0, stream>>>(S, WT, PGt, r, w1, q, pbgb,
                                              th_w, th_b, W_w, W_b, u1v, w2v, c0);
    // Afull[f][e] = (1/N) sum_c1 Rt[e][c1] WT[f][c1] + u1 w1^T + u2 w2^T
    mfma_gemm<4><<<dim3(4, 4, Bn), blk, 0, stream>>>(
        Rt, Cc, sq_bs, WT, Cc, 0, Afull, Cc, sq_bs, Cc, 1.0f / (float)Nsp,
        nullptr, 0, nullptr, nullptr, u1v, w1, u2v, w2v);
    // z[f][n] = sum_e Afull[f][e] xT[n][e] + c0[b][f] + x (fp32) ; bf16 store + stats
    mfma_gemm<2><<<dim3(25, 4, Bn), blk, 0, stream>>>(
        xT, Cc, xT_bs, Afull, Cc, sq_bs, z16, Nsp, (long)Cc * Nsp, Cc, 1.0f,
        c0, Cc, x, stats, nullptr, nullptr, nullptr, nullptr);
    finalize_stats<<<dim3(1), dim3(Cc), 0, stream>>>(stats, mstd);
    bnorm_apply<<<dim3((Bn * Cc * (Nsp / 8) + 255) / 256), blk, 0, stream>>>(
        z16, mstd, gamma, beta, out);
}